// Round 5
// baseline (605.646 us; speedup 1.0000x reference)
//
#include <hip/hip_runtime.h>
#include <hip/hip_bf16.h>

#define BB 8
#define CC 256
#define HH 128
#define WW 128
#define KS 9
#define NPIX (BB*HH*WW)   // 131072
#define KDIM (4*CC)       // 1024

typedef __attribute__((ext_vector_type(8))) short bf16x8;
typedef __attribute__((ext_vector_type(4))) float f32x4;

static __device__ __forceinline__ unsigned short f2bf(float f) {
  union { float f; unsigned u; } v; v.f = f;
  unsigned r = v.u + 0x7FFF + ((v.u >> 16) & 1);   // RNE
  return (unsigned short)(r >> 16);
}
static __device__ __forceinline__ float bf2f(unsigned short u) {
  union { unsigned u; float f; } v; v.u = ((unsigned)u) << 16;
  return v.f;
}

// global -> LDS direct copy, 16B per lane
static __device__ __forceinline__ void gload_lds16(const void* g, void* l) {
  __builtin_amdgcn_global_load_lds(
      (const __attribute__((address_space(1))) void*)g,
      (__attribute__((address_space(3))) void*)l, 16, 0, 0);
}

// ---------------------------------------------------------------------------
// Prep A': A'[o][k'] bf16, k' = c*4 + t, from wproj[o][t*256 + c] (fp32)
// ---------------------------------------------------------------------------
__global__ void prep_kernel(const float* __restrict__ wproj,
                            unsigned short* __restrict__ Ap) {
  int idx = blockIdx.x * 256 + threadIdx.x;    // 0 .. 262143
  int o  = idx >> 10;
  int kp = idx & 1023;
  int c  = kp >> 2;
  int t  = kp & 3;
  Ap[idx] = f2bf(wproj[o * 1024 + t * 256 + c]);
}

// ---------------------------------------------------------------------------
// Prep W: wt[cv][k][c] fp32 (c-contiguous for lane=c conv reads)
// ---------------------------------------------------------------------------
__global__ void wprep_kernel(const float* __restrict__ wh1,
                             const float* __restrict__ wh2,
                             const float* __restrict__ wv1,
                             const float* __restrict__ wv2,
                             float* __restrict__ wt) {
  int idx = blockIdx.x * 256 + threadIdx.x;    // 0..9215
  int c = idx & 255;
  int q = idx >> 8;          // 0..35, block-uniform
  int cv = q / 9, k = q % 9;
  const float* src = (cv == 0) ? wh1 : (cv == 1) ? wh2 : (cv == 2) ? wv1 : wv2;
  wt[idx] = src[c * KS + k];
}

// ---------------------------------------------------------------------------
// Transpose: x[b][c][h][w] fp32 -> x_t[b][hw][c] bf16. 64x64 LDS tile.
// ---------------------------------------------------------------------------
__global__ __launch_bounds__(256)
void transpose_kernel(const float* __restrict__ x,
                      unsigned short* __restrict__ xt) {
  __shared__ float lds[64][65];
  int g   = blockIdx.x;             // 8192 = 8b x 4ct x 256hwt
  int b   = g >> 10;
  int r   = g & 1023;
  int ct  = r >> 8;
  int hwt = r & 255;
  int c0  = ct * 64, hw0 = hwt * 64;
  const float* in = x + (size_t)b * CC * (HH * WW);
  unsigned short* outp = xt + (size_t)b * (HH * WW) * CC;

  int tr  = threadIdx.x >> 4;        // 0..15
  int tc4 = (threadIdx.x & 15) * 4;  // 0,4..60

#pragma unroll
  for (int s = 0; s < 4; ++s) {
    int row = tr + s * 16;           // c-local
    float4 v = *(const float4*)(in + (size_t)(c0 + row) * (HH * WW) + hw0 + tc4);
    lds[row][tc4 + 0] = v.x; lds[row][tc4 + 1] = v.y;
    lds[row][tc4 + 2] = v.z; lds[row][tc4 + 3] = v.w;
  }
  __syncthreads();
#pragma unroll
  for (int s = 0; s < 4; ++s) {
    int row_o = tr + s * 16;         // hw-local
    ushort4 o;
    o.x = f2bf(lds[tc4 + 0][row_o]);
    o.y = f2bf(lds[tc4 + 1][row_o]);
    o.z = f2bf(lds[tc4 + 2][row_o]);
    o.w = f2bf(lds[tc4 + 3][row_o]);
    *(ushort4*)(outp + (size_t)(hw0 + row_o) * CC + c0 + tc4) = o;
  }
}

// ---------------------------------------------------------------------------
// Conv v4: reads x_t (lane = c, fully coalesced), 9-reg vertical sliding
// window, horizontal window via coalesced L1-hit loads. No LDS, no barriers.
// Block = (b, w, h-strip of 32); 256 thr = 256 channels.
// Stores Y[p][c*4..c*4+3]: 8B/lane, 512B contiguous per wave.
// ---------------------------------------------------------------------------
__global__ __launch_bounds__(256)
void conv_kernel(const unsigned short* __restrict__ xt,
                 const float* __restrict__ wt,
                 unsigned short* __restrict__ Y) {
  int g  = blockIdx.x;
  int sb = (g & 7) * 512 + (g >> 3);   // XCD-chunked (4096 % 8 == 0)
  int w  = sb & 127;
  int tq = sb >> 7;                    // 0..31
  int hs = tq & 3;
  int b  = tq >> 2;
  int c  = threadIdx.x;

  float W1[KS], W2[KS], W3[KS], W4[KS];
#pragma unroll
  for (int k = 0; k < KS; ++k) {
    W1[k] = wt[(0 * KS + k) * CC + c];
    W2[k] = wt[(1 * KS + k) * CC + c];
    W3[k] = wt[(2 * KS + k) * CC + c];
    W4[k] = wt[(3 * KS + k) * CC + c];
  }

  const unsigned short* xb = xt + (size_t)b * (HH * WW) * CC;
  int h0 = hs * 32;

  float vwin[9];
#pragma unroll
  for (int i = 0; i < 8; ++i) {
    int row = h0 - 4 + i;
    vwin[i] = (row >= 0) ? bf2f(xb[(size_t)(row * WW + w) * CC + c]) : 0.f;
  }

#pragma unroll
  for (int s = 0; s < 32; ++s) {
    int h  = h0 + s;
    int rv = h + 4;
    vwin[8] = (rv < HH) ? bf2f(xb[(size_t)(rv * WW + w) * CC + c]) : 0.f;

    float hwin[9];
#pragma unroll
    for (int j = 0; j < 9; ++j) {
      if (j == 4) { hwin[j] = vwin[4]; continue; }
      int wp = w - 4 + j;                       // block-uniform predicate
      hwin[j] = (wp >= 0 && wp < WW) ? bf2f(xb[(size_t)(h * WW + wp) * CC + c]) : 0.f;
    }

    float s1 = 0.f, s2 = 0.f, s3 = 0.f, s4 = 0.f;
#pragma unroll
    for (int k = 0; k < KS; ++k) {
      s1 = fmaf(hwin[k], W1[k], s1);
      s2 = fmaf(hwin[k], W2[k], s2);
      s3 = fmaf(vwin[k], W3[k], s3);
      s4 = fmaf(vwin[k], W4[k], s4);
    }
    unsigned u0 = (unsigned)f2bf(s1) | ((unsigned)f2bf(s2) << 16);
    unsigned u1 = (unsigned)f2bf(s3) | ((unsigned)f2bf(s4) << 16);
    size_t p = (size_t)(b * (HH * WW) + h * WW + w);
    *(uint2*)(Y + p * KDIM + c * 4) = make_uint2(u0, u1);

#pragma unroll
    for (int i = 0; i < 8; ++i) vwin[i] = vwin[i + 1];
  }
}

// ---------------------------------------------------------------------------
// GEMM v3: out = relu(A'(256x1024) @ Y^T), BM=256 (Y read ONCE), BN=128,
// BK=64, 512 thr = 8 waves (4M x 2N), m97-style gload_lds staging.
// Grid 1024 = one block per (b,h) pixel row, XCD-chunked.
// ---------------------------------------------------------------------------
__global__ __launch_bounds__(512)
void gemm_kernel(const unsigned short* __restrict__ Ap,
                 const unsigned short* __restrict__ Yg,
                 float* __restrict__ out) {
  __shared__ short As[256 * 64];   // 32 KB
  __shared__ short Bs[128 * 64];   // 16 KB

  int bid = blockIdx.x;
  int pt  = (bid & 7) * 128 + (bid >> 3);   // 1024 = 8 XCD x 128
  int tid  = threadIdx.x;
  int lane = tid & 63;
  int wv   = tid >> 6;
  int om   = wv & 3;                 // 0..3 : o base om*64
  int pn   = wv >> 2;                // 0..1 : p base pn*64
  int l15  = lane & 15;
  int kseg = lane >> 4;

  const short* A  = (const short*)Ap;
  const short* Bg = (const short*)Yg + (size_t)pt * 128 * KDIM;

  int srow = tid >> 3;               // 0..63
  int skc  = (tid & 7) * 8;

  f32x4 acc[4][4] = {};

  for (int k0 = 0; k0 < KDIM; k0 += 64) {
#pragma unroll
    for (int i = 0; i < 4; ++i) {
      int rr = i * 64 + srow;
      gload_lds16(A + (size_t)rr * KDIM + k0 + skc, &As[rr * 64 + skc]);
    }
#pragma unroll
    for (int i = 0; i < 2; ++i) {
      int rr = i * 64 + srow;
      gload_lds16(Bg + (size_t)rr * KDIM + k0 + skc, &Bs[rr * 64 + skc]);
    }
    __syncthreads();
#pragma unroll
    for (int kk = 0; kk < 2; ++kk) {
      bf16x8 af[4], bfr[4];
#pragma unroll
      for (int m = 0; m < 4; ++m)
        af[m] = *(const bf16x8*)&As[(om * 64 + m * 16 + l15) * 64 + kk * 32 + kseg * 8];
#pragma unroll
      for (int n = 0; n < 4; ++n)
        bfr[n] = *(const bf16x8*)&Bs[(pn * 64 + n * 16 + l15) * 64 + kk * 32 + kseg * 8];
#pragma unroll
      for (int m = 0; m < 4; ++m)
#pragma unroll
        for (int n = 0; n < 4; ++n)
          acc[m][n] = __builtin_amdgcn_mfma_f32_16x16x32_bf16(af[m], bfr[n],
                                                              acc[m][n], 0, 0, 0);
    }
    __syncthreads();
  }

  int b = pt >> 7, h = pt & 127;
#pragma unroll
  for (int m = 0; m < 4; ++m) {
#pragma unroll
    for (int n = 0; n < 4; ++n) {
#pragma unroll
      for (int r = 0; r < 4; ++r) {
        int o = om * 64 + m * 16 + kseg * 4 + r;
        int w = pn * 64 + n * 16 + l15;
        out[((size_t)(b * 256 + o) << 14) + (h << 7) + w] =
            fmaxf(acc[m][n][r], 0.f);
      }
    }
  }
}

extern "C" void kernel_launch(void* const* d_in, const int* in_sizes, int n_in,
                              void* d_out, int out_size, void* d_ws, size_t ws_size,
                              hipStream_t stream) {
  (void)in_sizes; (void)n_in; (void)out_size; (void)ws_size;
  const float* x     = (const float*)d_in[0];
  const float* wh1   = (const float*)d_in[1];
  const float* wh2   = (const float*)d_in[2];
  const float* wv1   = (const float*)d_in[3];
  const float* wv2   = (const float*)d_in[4];
  const float* wproj = (const float*)d_in[5];
  float* out = (float*)d_out;

  // ws layout: Y (268.4 MB) | x_t bf16 (67.1 MB) | Ap (512 KB) | wt (36 KB)
  char* wsb = (char*)d_ws;
  unsigned short* Yg = (unsigned short*)wsb;
  unsigned short* Xt = (unsigned short*)(wsb + (size_t)NPIX * KDIM * 2);
  unsigned short* Ap = (unsigned short*)(wsb + (size_t)NPIX * KDIM * 2
                                             + (size_t)NPIX * CC * 2);
  float* Wt = (float*)(wsb + (size_t)NPIX * KDIM * 2
                           + (size_t)NPIX * CC * 2 + (size_t)CC * KDIM * 2);

  hipLaunchKernelGGL(prep_kernel, dim3(1024), dim3(256), 0, stream, wproj, Ap);
  hipLaunchKernelGGL(wprep_kernel, dim3(36), dim3(256), 0, stream,
                     wh1, wh2, wv1, wv2, Wt);
  hipLaunchKernelGGL(transpose_kernel, dim3(8192), dim3(256), 0, stream, x, Xt);
  hipLaunchKernelGGL(conv_kernel, dim3(4096), dim3(256), 0, stream, Xt, Wt, Yg);
  hipLaunchKernelGGL(gemm_kernel, dim3(1024), dim3(512), 0, stream, Ap, Yg, out);
}

// Round 6
// 590.748 us; speedup vs baseline: 1.0252x; 1.0252x over previous
//
#include <hip/hip_runtime.h>
#include <hip/hip_bf16.h>

#define BB 8
#define CC 256
#define HH 128
#define WW 128
#define KS 9
#define NPIX (BB*HH*WW)   // 131072
#define KDIM (4*CC)       // 1024

typedef __attribute__((ext_vector_type(8))) short bf16x8;
typedef __attribute__((ext_vector_type(4))) float f32x4;

static __device__ __forceinline__ unsigned short f2bf(float f) {
  union { float f; unsigned u; } v; v.f = f;
  unsigned r = v.u + 0x7FFF + ((v.u >> 16) & 1);   // RNE
  return (unsigned short)(r >> 16);
}
static __device__ __forceinline__ float bf2f(unsigned short u) {
  union { unsigned u; float f; } v; v.u = ((unsigned)u) << 16;
  return v.f;
}

// global -> LDS direct copy, 16B per lane
static __device__ __forceinline__ void gload_lds16(const void* g, void* l) {
  __builtin_amdgcn_global_load_lds(
      (const __attribute__((address_space(1))) void*)g,
      (__attribute__((address_space(3))) void*)l, 16, 0, 0);
}

// ---------------------------------------------------------------------------
// Prep A': A'[o][k'] bf16, k' = c*4 + t, from wproj[o][t*256 + c] (fp32)
// ---------------------------------------------------------------------------
__global__ void prep_kernel(const float* __restrict__ wproj,
                            unsigned short* __restrict__ Ap) {
  int idx = blockIdx.x * 256 + threadIdx.x;    // 0 .. 262143
  int o  = idx >> 10;
  int kp = idx & 1023;
  int c  = kp >> 2;
  int t  = kp & 3;
  Ap[idx] = f2bf(wproj[o * 1024 + t * 256 + c]);
}

// ---------------------------------------------------------------------------
// Prep W: wt[cv][k][c] fp32 (c-contiguous for lane=c conv reads)
// ---------------------------------------------------------------------------
__global__ void wprep_kernel(const float* __restrict__ wh1,
                             const float* __restrict__ wh2,
                             const float* __restrict__ wv1,
                             const float* __restrict__ wv2,
                             float* __restrict__ wt) {
  int idx = blockIdx.x * 256 + threadIdx.x;    // 0..9215
  int c = idx & 255;
  int q = idx >> 8;          // 0..35, block-uniform
  int cv = q / 9, k = q % 9;
  const float* src = (cv == 0) ? wh1 : (cv == 1) ? wh2 : (cv == 2) ? wv1 : wv2;
  wt[idx] = src[c * KS + k];
}

// ---------------------------------------------------------------------------
// Transpose: x[b][c][h][w] fp32 -> x_t[b][hw][c] bf16. 64x64 LDS tile.
// (unchanged this round -- will surface in top-5 now; fix next if slow)
// ---------------------------------------------------------------------------
__global__ __launch_bounds__(256)
void transpose_kernel(const float* __restrict__ x,
                      unsigned short* __restrict__ xt) {
  __shared__ float lds[64][65];
  int g   = blockIdx.x;             // 8192 = 8b x 4ct x 256hwt
  int b   = g >> 10;
  int r   = g & 1023;
  int ct  = r >> 8;
  int hwt = r & 255;
  int c0  = ct * 64, hw0 = hwt * 64;
  const float* in = x + (size_t)b * CC * (HH * WW);
  unsigned short* outp = xt + (size_t)b * (HH * WW) * CC;

  int tr  = threadIdx.x >> 4;        // 0..15
  int tc4 = (threadIdx.x & 15) * 4;  // 0,4..60

#pragma unroll
  for (int s = 0; s < 4; ++s) {
    int row = tr + s * 16;           // c-local
    float4 v = *(const float4*)(in + (size_t)(c0 + row) * (HH * WW) + hw0 + tc4);
    lds[row][tc4 + 0] = v.x; lds[row][tc4 + 1] = v.y;
    lds[row][tc4 + 2] = v.z; lds[row][tc4 + 3] = v.w;
  }
  __syncthreads();
#pragma unroll
  for (int s = 0; s < 4; ++s) {
    int row_o = tr + s * 16;         // hw-local
    ushort4 o;
    o.x = f2bf(lds[tc4 + 0][row_o]);
    o.y = f2bf(lds[tc4 + 1][row_o]);
    o.z = f2bf(lds[tc4 + 2][row_o]);
    o.w = f2bf(lds[tc4 + 3][row_o]);
    *(ushort4*)(outp + (size_t)(hw0 + row_o) * CC + c0 + tc4) = o;
  }
}

// ---------------------------------------------------------------------------
// Conv v5: block = (b, h, w-strip of 32); 256 thr = 256 channels.
// w streams inside the block => Y writes are a 64 KB CONTIGUOUS stream per
// block (was: 512B chunks at 256KB stride). Horizontal window slides in regs;
// vertical taps re-loaded each step (L2-hot). Same VMEM count as v4 ->
// clean A/B on write order.
// ---------------------------------------------------------------------------
__global__ __launch_bounds__(256)
void conv_kernel(const unsigned short* __restrict__ xt,
                 const float* __restrict__ wt,
                 unsigned short* __restrict__ Y) {
  int g    = blockIdx.x;           // 4096 = 8b x 128h x 4ws
  int b    = g & 7;                // consecutive g -> different XCD ~= b
  int rest = g >> 3;               // 0..511
  int h    = rest >> 2;
  int ws   = rest & 3;
  int c    = threadIdx.x;

  float W1[KS], W2[KS], W3[KS], W4[KS];
#pragma unroll
  for (int k = 0; k < KS; ++k) {
    W1[k] = wt[(0 * KS + k) * CC + c];
    W2[k] = wt[(1 * KS + k) * CC + c];
    W3[k] = wt[(2 * KS + k) * CC + c];
    W4[k] = wt[(3 * KS + k) * CC + c];
  }

  const unsigned short* xb = xt + (size_t)b * (HH * WW) * CC;
  int w0 = ws * 32;

  // horizontal ring: hwin[i] = x(h, w-4+i), i=0..8, for current w
  float hwin[9];
#pragma unroll
  for (int i = 0; i < 9; ++i) {
    int wp = w0 - 4 + i;
    hwin[i] = (wp >= 0 && wp < WW) ? bf2f(xb[((size_t)h * WW + wp) * CC + c]) : 0.f;
  }

  unsigned short* ybase = Y + ((size_t)((b * HH + h) * WW)) * KDIM + c * 4;

#pragma unroll 4
  for (int s = 0; s < 32; ++s) {
    int w = w0 + s;
    // vertical taps (center shared with hwin[4])
    float vv[9];
#pragma unroll
    for (int k = 0; k < 9; ++k) {
      if (k == 4) { vv[k] = hwin[4]; continue; }
      int r = h - 4 + k;                      // block-uniform predicate
      vv[k] = (r >= 0 && r < HH) ? bf2f(xb[((size_t)r * WW + w) * CC + c]) : 0.f;
    }

    float s1 = 0.f, s2 = 0.f, s3 = 0.f, s4 = 0.f;
#pragma unroll
    for (int k = 0; k < KS; ++k) {
      s1 = fmaf(hwin[k], W1[k], s1);
      s2 = fmaf(hwin[k], W2[k], s2);
      s3 = fmaf(vv[k],   W3[k], s3);
      s4 = fmaf(vv[k],   W4[k], s4);
    }
    unsigned u0 = (unsigned)f2bf(s1) | ((unsigned)f2bf(s2) << 16);
    unsigned u1 = (unsigned)f2bf(s3) | ((unsigned)f2bf(s4) << 16);
    *(uint2*)(ybase + (size_t)w * KDIM) = make_uint2(u0, u1);

    // slide horizontal window
#pragma unroll
    for (int i = 0; i < 8; ++i) hwin[i] = hwin[i + 1];
    int wn = w + 5;
    hwin[8] = (wn < WW) ? bf2f(xb[((size_t)h * WW + wn) * CC + c]) : 0.f;
  }
}

// ---------------------------------------------------------------------------
// GEMM v4: out = relu(A'(256x1024) @ Y^T), BM=256, BN=128, BK=64,
// 512 thr = 8 waves (4M x 2N), m97-style gload_lds staging.
// NEW: epilogue restaged through LDS -> 512B coalesced out rows
// (was scattered 64B pieces). Grid 1024, XCD-chunked by pt.
// ---------------------------------------------------------------------------
__global__ __launch_bounds__(512)
void gemm_kernel(const unsigned short* __restrict__ Ap,
                 const unsigned short* __restrict__ Yg,
                 float* __restrict__ out) {
  __shared__ short As[256 * 64];   // 32 KB (reused as f32 staging in epilogue)
  __shared__ short Bs[128 * 64];   // 16 KB

  int bid = blockIdx.x;
  int pt  = (bid & 7) * 128 + (bid >> 3);   // 1024 = 8 XCD x 128
  int tid  = threadIdx.x;
  int lane = tid & 63;
  int wv   = tid >> 6;
  int om   = wv & 3;                 // 0..3 : o base om*64
  int pn   = wv >> 2;                // 0..1 : p base pn*64
  int l15  = lane & 15;
  int kseg = lane >> 4;

  const short* A  = (const short*)Ap;
  const short* Bg = (const short*)Yg + (size_t)pt * 128 * KDIM;

  int srow = tid >> 3;               // 0..63
  int skc  = (tid & 7) * 8;

  f32x4 acc[4][4] = {};

  for (int k0 = 0; k0 < KDIM; k0 += 64) {
#pragma unroll
    for (int i = 0; i < 4; ++i) {
      int rr = i * 64 + srow;
      gload_lds16(A + (size_t)rr * KDIM + k0 + skc, &As[rr * 64 + skc]);
    }
#pragma unroll
    for (int i = 0; i < 2; ++i) {
      int rr = i * 64 + srow;
      gload_lds16(Bg + (size_t)rr * KDIM + k0 + skc, &Bs[rr * 64 + skc]);
    }
    __syncthreads();
#pragma unroll
    for (int kk = 0; kk < 2; ++kk) {
      bf16x8 af[4], bfr[4];
#pragma unroll
      for (int m = 0; m < 4; ++m)
        af[m] = *(const bf16x8*)&As[(om * 64 + m * 16 + l15) * 64 + kk * 32 + kseg * 8];
#pragma unroll
      for (int n = 0; n < 4; ++n)
        bfr[n] = *(const bf16x8*)&Bs[(pn * 64 + n * 16 + l15) * 64 + kk * 32 + kseg * 8];
#pragma unroll
      for (int m = 0; m < 4; ++m)
#pragma unroll
        for (int n = 0; n < 4; ++n)
          acc[m][n] = __builtin_amdgcn_mfma_f32_16x16x32_bf16(af[m], bfr[n],
                                                              acc[m][n], 0, 0, 0);
    }
    __syncthreads();
  }

  // Epilogue: restage through LDS, 32 o-rows per chunk, coalesced 512B rows.
  float* Ls = (float*)As;            // 32*132*4 = 16.9 KB <= 32 KB
  const int LP = 132;                // +4 pad: kseg rows land 16 banks apart
  int b2 = pt >> 7, h2 = pt & 127;
  int er = tid >> 4;                 // 0..31  (o-row within chunk)
  int ec = (tid & 15) * 8;           // 0..120 (w position)
  size_t obase = ((size_t)(b2 * 256) << 14) + (h2 << 7);

#pragma unroll
  for (int oc = 0; oc < 8; ++oc) {
    __syncthreads();
    if (om == (oc >> 1)) {
      int mb = (oc & 1) * 2;
#pragma unroll
      for (int mm = 0; mm < 2; ++mm) {
#pragma unroll
        for (int n = 0; n < 4; ++n) {
#pragma unroll
          for (int r = 0; r < 4; ++r) {
            int row = mm * 16 + kseg * 4 + r;          // 0..31
            int col = pn * 64 + n * 16 + l15;          // 0..127
            Ls[row * LP + col] = acc[mb + mm][n][r];
          }
        }
      }
    }
    __syncthreads();
    float4 v0 = *(const float4*)&Ls[er * LP + ec];
    float4 v1 = *(const float4*)&Ls[er * LP + ec + 4];
    size_t oaddr = obase + ((size_t)(oc * 32 + er) << 14) + ec;
    *(float4*)&out[oaddr] = make_float4(fmaxf(v0.x, 0.f), fmaxf(v0.y, 0.f),
                                        fmaxf(v0.z, 0.f), fmaxf(v0.w, 0.f));
    *(float4*)&out[oaddr + 4] = make_float4(fmaxf(v1.x, 0.f), fmaxf(v1.y, 0.f),
                                            fmaxf(v1.z, 0.f), fmaxf(v1.w, 0.f));
  }
}

extern "C" void kernel_launch(void* const* d_in, const int* in_sizes, int n_in,
                              void* d_out, int out_size, void* d_ws, size_t ws_size,
                              hipStream_t stream) {
  (void)in_sizes; (void)n_in; (void)out_size; (void)ws_size;
  const float* x     = (const float*)d_in[0];
  const float* wh1   = (const float*)d_in[1];
  const float* wh2   = (const float*)d_in[2];
  const float* wv1   = (const float*)d_in[3];
  const float* wv2   = (const float*)d_in[4];
  const float* wproj = (const float*)d_in[5];
  float* out = (float*)d_out;

  // ws layout: Y (268.4 MB) | x_t bf16 (67.1 MB) | Ap (512 KB) | wt (36 KB)
  char* wsb = (char*)d_ws;
  unsigned short* Yg = (unsigned short*)wsb;
  unsigned short* Xt = (unsigned short*)(wsb + (size_t)NPIX * KDIM * 2);
  unsigned short* Ap = (unsigned short*)(wsb + (size_t)NPIX * KDIM * 2
                                             + (size_t)NPIX * CC * 2);
  float* Wt = (float*)(wsb + (size_t)NPIX * KDIM * 2
                           + (size_t)NPIX * CC * 2 + (size_t)CC * KDIM * 2);

  hipLaunchKernelGGL(prep_kernel, dim3(1024), dim3(256), 0, stream, wproj, Ap);
  hipLaunchKernelGGL(wprep_kernel, dim3(36), dim3(256), 0, stream,
                     wh1, wh2, wv1, wv2, Wt);
  hipLaunchKernelGGL(transpose_kernel, dim3(8192), dim3(256), 0, stream, x, Xt);
  hipLaunchKernelGGL(conv_kernel, dim3(4096), dim3(256), 0, stream, Xt, Wt, Yg);
  hipLaunchKernelGGL(gemm_kernel, dim3(1024), dim3(512), 0, stream, Ap, Yg, out);
}